// Round 1
// baseline (662.523 us; speedup 1.0000x reference)
//
#include <hip/hip_runtime.h>
#include <cmath>
#include <complex>
#include <cstring>
#include <algorithm>

#define WN      11264
#define DIM_IN  288
#define DIM_SHD 9
#define NB      10
#define NH      16
#define EPB     32
#define BLOCK   256
#define NINSTR  11

// Wigner-3j coefficients (pw pre-folded), computed host-side each launch.
__device__ float g_C[NINSTR][125];

template<int D1,int D2,int D3,int OFF1,int OFF2,int SB>
__device__ __forceinline__ void run_instr(
    int ins, int tid, int e0, int g, int q,
    const float* __restrict__ xg,
    const float* __restrict__ W2, const float* __restrict__ b2,
    const float (&s_sh)[EPB][12], const float (&s_h)[EPB][17],
    float (&s_z)[EPB][161], float acc[9][4])
{
  __syncthreads();   // protects s_z reuse (and phase-1 writes on first call)
  const float* __restrict__ Cp = g_C[ins];
  // ---- z phase: 32 edges x 32 channels = 1024 tasks over 256 threads ----
  #pragma unroll
  for (int s = 0; s < 4; ++s) {
    int id = tid + s * BLOCK;
    int zg = id >> 5, u = id & 31;
    const float* xe = xg + (size_t)(e0 + zg) * DIM_IN + OFF1 + u * D1;
    float zk[D3];
    #pragma unroll
    for (int k = 0; k < D3; ++k) zk[k] = 0.f;
    #pragma unroll
    for (int i = 0; i < D1; ++i) {
      float xv = xe[i];
      #pragma unroll
      for (int j = 0; j < D2; ++j) {
        float pr = xv * s_sh[zg][OFF2 + j];
        #pragma unroll
        for (int k = 0; k < D3; ++k)
          zk[k] = fmaf(Cp[(i * D2 + j) * D3 + k], pr, zk[k]);
      }
    }
    #pragma unroll
    for (int k = 0; k < D3; ++k) s_z[zg][u * 5 + k] = zk[k];
  }
  __syncthreads();
  // ---- fused weight-gen + contraction ----
  const float* W2c = W2 + ins * 1024 + q * 4;
  const float* b2c = b2 + ins * 1024 + q * 4;
  for (int u = 0; u < 32; ++u) {
    float4 wv = *reinterpret_cast<const float4*>(b2c + u * 32);
    #pragma unroll
    for (int t = 0; t < NH; ++t) {
      float4 wr = *reinterpret_cast<const float4*>(W2c + (size_t)t * WN + u * 32);
      float hv = s_h[g][t];
      wv.x = fmaf(hv, wr.x, wv.x);
      wv.y = fmaf(hv, wr.y, wv.y);
      wv.z = fmaf(hv, wr.z, wv.z);
      wv.w = fmaf(hv, wr.w, wv.w);
    }
    #pragma unroll
    for (int k = 0; k < D3; ++k) {
      float zv = s_z[g][u * 5 + k];   // pw already folded into C -> z
      acc[SB + k][0] = fmaf(wv.x, zv, acc[SB + k][0]);
      acc[SB + k][1] = fmaf(wv.y, zv, acc[SB + k][1]);
      acc[SB + k][2] = fmaf(wv.z, zv, acc[SB + k][2]);
      acc[SB + k][3] = fmaf(wv.w, zv, acc[SB + k][3]);
    }
  }
}

__global__ __launch_bounds__(BLOCK) void conv_kernel(
    const float* __restrict__ xg, const float* __restrict__ shg,
    const float* __restrict__ dist, const float* __restrict__ freq,
    const float* __restrict__ W1, const float* __restrict__ b1,
    const float* __restrict__ W2, const float* __restrict__ b2,
    float* __restrict__ out)
{
  __shared__ float s_sh[EPB][12];
  __shared__ float s_basis[EPB][NB];
  __shared__ float s_h[EPB][17];
  __shared__ float s_z[EPB][161];

  const int tid = threadIdx.x;
  const int e0 = blockIdx.x * EPB;
  const int g = tid >> 3, q = tid & 7;

  // ---- phase 1: sh, radial basis ----
  for (int i = tid; i < EPB * DIM_SHD; i += BLOCK) {
    int zg = i / DIM_SHD, c = i - zg * DIM_SHD;
    s_sh[zg][c] = shg[(size_t)(e0 + zg) * DIM_SHD + c];
  }
  for (int i = tid; i < EPB * NB; i += BLOCK) {
    int zg = i / NB, n = i - zg * NB;
    float d  = dist[e0 + zg];
    float xv = d * 0.25f;
    float x2 = xv * xv, x4 = x2 * x2, x5 = x4 * xv;
    float env = 1.0f / xv + x5 * fmaf(xv, fmaf(xv, -21.0f, 48.0f), -28.0f);
    env = (xv < 1.0f) ? env : 0.0f;
    s_basis[zg][n] = env * sinf(freq[n] * xv);
  }
  __syncthreads();
  // ---- radial MLP hidden layer ----
  for (int i = tid; i < EPB * NH; i += BLOCK) {
    int zg = i >> 4, t = i & 15;
    float v = b1[t];
    #pragma unroll
    for (int n = 0; n < NB; ++n) v = fmaf(s_basis[zg][n], W1[n * NH + t], v);
    s_h[zg][t] = v / (1.0f + expf(-v));   // silu
  }

  float acc[9][4];
  #pragma unroll
  for (int a = 0; a < 9; ++a) { acc[a][0]=acc[a][1]=acc[a][2]=acc[a][3]=0.f; }

  //               D1 D2 D3 OFF1 OFF2 SB   ins
  run_instr<1,1,1,   0, 0, 0>( 0, tid, e0, g, q, xg, W2, b2, s_sh, s_h, s_z, acc);
  run_instr<1,3,3,   0, 1, 1>( 1, tid, e0, g, q, xg, W2, b2, s_sh, s_h, s_z, acc);
  run_instr<1,5,5,   0, 4, 4>( 2, tid, e0, g, q, xg, W2, b2, s_sh, s_h, s_z, acc);
  run_instr<3,1,3,  32, 0, 1>( 3, tid, e0, g, q, xg, W2, b2, s_sh, s_h, s_z, acc);
  run_instr<3,3,1,  32, 1, 0>( 4, tid, e0, g, q, xg, W2, b2, s_sh, s_h, s_z, acc);
  run_instr<3,3,5,  32, 1, 4>( 5, tid, e0, g, q, xg, W2, b2, s_sh, s_h, s_z, acc);
  run_instr<3,5,3,  32, 4, 1>( 6, tid, e0, g, q, xg, W2, b2, s_sh, s_h, s_z, acc);
  run_instr<5,1,5, 128, 0, 4>( 7, tid, e0, g, q, xg, W2, b2, s_sh, s_h, s_z, acc);
  run_instr<5,3,3, 128, 1, 1>( 8, tid, e0, g, q, xg, W2, b2, s_sh, s_h, s_z, acc);
  run_instr<5,5,1, 128, 4, 0>( 9, tid, e0, g, q, xg, W2, b2, s_sh, s_h, s_z, acc);
  run_instr<5,5,5, 128, 4, 4>(10, tid, e0, g, q, xg, W2, b2, s_sh, s_h, s_z, acc);

  // ---- write out: [e][288] = [0:32) l0 | [32:128) l1 | [128:288) l2 ----
  float* oe = out + (size_t)(e0 + g) * DIM_IN;
  *reinterpret_cast<float4*>(oe + 4 * q) =
      make_float4(acc[0][0], acc[0][1], acc[0][2], acc[0][3]);
  float t1[12];
  #pragma unroll
  for (int j = 0; j < 4; ++j)
    #pragma unroll
    for (int k = 0; k < 3; ++k) t1[j * 3 + k] = acc[1 + k][j];
  #pragma unroll
  for (int v = 0; v < 3; ++v)
    *reinterpret_cast<float4*>(oe + 32 + 12 * q + 4 * v) =
        *reinterpret_cast<float4*>(t1 + 4 * v);
  float t2[20];
  #pragma unroll
  for (int j = 0; j < 4; ++j)
    #pragma unroll
    for (int k = 0; k < 5; ++k) t2[j * 5 + k] = acc[4 + k][j];
  #pragma unroll
  for (int v = 0; v < 5; ++v)
    *reinterpret_cast<float4*>(oe + 128 + 20 * q + 4 * v) =
        *reinterpret_cast<float4*>(t2 + 4 * v);
}

// ===================== host-side Wigner-3j (mirrors reference) =====================
typedef std::complex<double> cd;

static double factd(int n) { double r = 1; for (int i = 2; i <= n; ++i) r *= i; return r; }

static double su2_cg(int j1, int j2, int j3, int m1, int m2, int m3) {
  if (m3 != m1 + m2) return 0.0;
  int vmin = std::max(std::max(-j1 + j2 + m3, -j1 + m1), 0);
  int vmax = std::min(std::min(j2 + j3 + m1, j3 - j1 + j2), j3 + m3);
  if (vmax < vmin) return 0.0;
  double c = std::sqrt(
      factd(2*j3+1) * factd(j3+j1-j2) * factd(j3-j1+j2) * factd(j1+j2-j3) / factd(j1+j2+j3+1)
      * factd(j3+m3) * factd(j3-m3)
      / (factd(j1+m1) * factd(j1-m1) * factd(j2+m2) * factd(j2-m2)));
  double s = 0.0;
  for (int v = vmin; v <= vmax; ++v) {
    double sg = ((v + j2 + m2) & 1) ? -1.0 : 1.0;
    s += sg * factd(j2+j3+m1-v) * factd(j1-m1+v)
         / (factd(v) * factd(j3-j1+j2-v) * factd(j3+m3-v) * factd(v+j1-j2-m3));
  }
  return c * s;
}

static void qmat(int l, cd q[5][5]) {
  for (int a = 0; a < 5; ++a) for (int b = 0; b < 5; ++b) q[a][b] = cd(0, 0);
  const double s = 1.0 / std::sqrt(2.0);
  for (int m = -l; m < 0; ++m) {
    q[l + m][l - m] = cd(s, 0);
    q[l + m][l + m] = cd(0, -s);
  }
  q[l][l] = cd(1, 0);
  for (int m = 1; m <= l; ++m) {
    double sg = (m & 1) ? -1.0 : 1.0;
    q[l + m][l + m] = cd(sg * s, 0);
    q[l + m][l - m] = cd(0, sg * s);
  }
  cd ph = (l == 0) ? cd(1, 0) : (l == 1) ? cd(0, -1) : cd(-1, 0);  // (-i)^l
  for (int a = 0; a < 5; ++a) for (int b = 0; b < 5; ++b) q[a][b] *= ph;
}

static void wigner3j(int l1, int l2, int l3, double C[5][5][5]) {
  int d1 = 2*l1+1, d2 = 2*l2+1, d3 = 2*l3+1;
  cd q1[5][5], q2[5][5], q3[5][5];
  qmat(l1, q1); qmat(l2, q2); qmat(l3, q3);
  double norm2 = 0;
  for (int j = 0; j < d1; ++j)
    for (int l = 0; l < d2; ++l)
      for (int n = 0; n < d3; ++n) {
        cd sum(0, 0);
        for (int i = 0; i < d1; ++i)
          for (int k = 0; k < d2; ++k)
            for (int m = 0; m < d3; ++m) {
              double cg = su2_cg(l1, l2, l3, i - l1, k - l2, m - l3);
              if (cg != 0.0) sum += q1[i][j] * q2[k][l] * std::conj(q3[m][n]) * cg;
            }
        C[j][l][n] = sum.real();
        norm2 += C[j][l][n] * C[j][l][n];
      }
  double nrm = std::sqrt(norm2);
  if (nrm > 0)
    for (int j = 0; j < d1; ++j)
      for (int l = 0; l < d2; ++l)
        for (int n = 0; n < d3; ++n) C[j][l][n] /= nrm;
}

static void build_C_host(float C_out[NINSTR][125]) {
  const int L1[NINSTR] = {0,0,0,1,1,1,1,2,2,2,2};
  const int L2[NINSTR] = {0,1,2,0,1,1,2,0,1,2,2};
  const int L3[NINSTR] = {0,1,2,1,0,2,1,2,1,0,2};
  std::memset(C_out, 0, sizeof(float) * NINSTR * 125);
  for (int ins = 0; ins < NINSTR; ++ins) {
    int l1 = L1[ins], l2 = L2[ins], l3 = L3[ins];
    int d1 = 2*l1+1, d2 = 2*l2+1, d3 = 2*l3+1;
    double C[5][5][5];
    wigner3j(l1, l2, l3, C);
    double fan = (l3 == 0) ? 96.0 : 128.0;           // fan-in per output irrep
    double pw = std::sqrt((2*l3+1) / fan);
    for (int i = 0; i < d1; ++i)
      for (int j = 0; j < d2; ++j)
        for (int k = 0; k < d3; ++k)
          C_out[ins][(i * d2 + j) * d3 + k] = (float)(pw * C[i][j][k]);
  }
}

extern "C" void kernel_launch(void* const* d_in, const int* in_sizes, int n_in,
                              void* d_out, int out_size, void* d_ws, size_t ws_size,
                              hipStream_t stream) {
  // persistent host buffer (graph replay re-reads it), refilled deterministically
  static float hC[NINSTR][125];
  build_C_host(hC);
  void* dC = nullptr;
  hipGetSymbolAddress(&dC, HIP_SYMBOL(g_C));
  hipMemcpyAsync(dC, hC, sizeof(hC), hipMemcpyHostToDevice, stream);

  const float* xg   = (const float*)d_in[0];
  const float* shg  = (const float*)d_in[1];
  const float* dist = (const float*)d_in[2];
  const float* freq = (const float*)d_in[3];
  const float* W1   = (const float*)d_in[4];
  const float* b1   = (const float*)d_in[5];
  const float* W2   = (const float*)d_in[6];
  const float* b2   = (const float*)d_in[7];
  float* out = (float*)d_out;

  int E = in_sizes[2];            // 16384
  int blocks = E / EPB;           // 512
  conv_kernel<<<blocks, BLOCK, 0, stream>>>(xg, shg, dist, freq, W1, b1, W2, b2, out);
}

// Round 2
// 195.419 us; speedup vs baseline: 3.3903x; 3.3903x over previous
//
#include <hip/hip_runtime.h>
#include <cmath>
#include <complex>
#include <cstring>
#include <algorithm>

#define DIM_IN  288
#define DIM_SHD 9
#define NB      10
#define NH      16
#define EPB     32
#define BLOCK   256
#define NINSTR  11
#define W2T_ELEMS (11264 * 16)

// Wigner-3j coefficients (pw pre-folded), computed host-side each launch.
__device__ float g_C[NINSTR][125];

// W2 transpose: W2t[((ins*32+u)*32+w)*16+t] = W2[t*11264 + ins*1024 + u*32 + w]
__global__ __launch_bounds__(256) void transpose_w2(const float* __restrict__ W2,
                                                    float* __restrict__ W2t) {
  int gid = blockIdx.x * 256 + threadIdx.x;
  if (gid < W2T_ELEMS) {
    int c = gid >> 4, t = gid & 15;
    W2t[gid] = W2[(size_t)t * 11264 + c];
  }
}

template<int INS,int D1,int D2,int D3,int OFF1,int OFF2,int SB>
__device__ __forceinline__ void run_instr(
    int tid, int e0, int gq, int w,
    const float* __restrict__ xg,
    const float* __restrict__ W2t, const float* __restrict__ b2,
    const float (&s_sh)[EPB][12],
    float* __restrict__ s_z,              // row stride 160: [e][k*32+u]
    const float (&h)[4][NH],
    float (&acc)[4][9])
{
  __syncthreads();   // s_z reuse guard (prev contraction readers done)

  const float* __restrict__ Cp = g_C[INS];   // uniform address -> s_load
  // ---- z phase: 32 edges x 32 u over 256 threads, 4 tasks each ----
  #pragma unroll
  for (int s = 0; s < 4; ++s) {
    int id = tid + s * BLOCK;
    int zg = id >> 5, u = id & 31;
    const float* xe = xg + (size_t)(e0 + zg) * DIM_IN + OFF1 + u * D1;
    float zk[D3];
    #pragma unroll
    for (int k = 0; k < D3; ++k) zk[k] = 0.f;
    #pragma unroll
    for (int i = 0; i < D1; ++i) {
      float xv = xe[i];
      #pragma unroll
      for (int j = 0; j < D2; ++j) {
        float pr = xv * s_sh[zg][OFF2 + j];
        #pragma unroll
        for (int k = 0; k < D3; ++k)
          zk[k] = fmaf(Cp[(i * D2 + j) * D3 + k], pr, zk[k]);
      }
    }
    #pragma unroll
    for (int k = 0; k < D3; ++k) s_z[zg * 160 + k * 32 + u] = zk[k];  // stride-1 lanes
  }
  __syncthreads();

  // ---- fused weight-gen + contraction ----
  // thread owns edges 4gq..4gq+3, column w (of 32) for every u
  const float* __restrict__ wbase = W2t + INS * 16384 + w * 16;
  const float* __restrict__ bbase = b2 + INS * 1024 + w;
  #pragma unroll 2
  for (int u = 0; u < 32; ++u) {
    const float* wp = wbase + u * 512;
    float4 A = *reinterpret_cast<const float4*>(wp);
    float4 Bv = *reinterpret_cast<const float4*>(wp + 4);
    float4 Cv = *reinterpret_cast<const float4*>(wp + 8);
    float4 Dv = *reinterpret_cast<const float4*>(wp + 12);
    float wt[16] = {A.x,A.y,A.z,A.w, Bv.x,Bv.y,Bv.z,Bv.w,
                    Cv.x,Cv.y,Cv.z,Cv.w, Dv.x,Dv.y,Dv.z,Dv.w};
    float bb = bbase[u * 32];
    #pragma unroll
    for (int e = 0; e < 4; ++e) {
      float wv = bb;
      #pragma unroll
      for (int t = 0; t < NH; ++t) wv = fmaf(h[e][t], wt[t], wv);
      #pragma unroll
      for (int k = 0; k < D3; ++k) {
        float zv = s_z[(4 * gq + e) * 160 + k * 32 + u];   // broadcast read
        acc[e][SB + k] = fmaf(wv, zv, acc[e][SB + k]);
      }
    }
  }
}

__global__ __launch_bounds__(BLOCK, 2) void conv_kernel(
    const float* __restrict__ xg, const float* __restrict__ shg,
    const float* __restrict__ dist, const float* __restrict__ freq,
    const float* __restrict__ W1, const float* __restrict__ b1,
    const float* __restrict__ W2t, const float* __restrict__ b2,
    float* __restrict__ out)
{
  __shared__ float s_pool[EPB * 288];     // s_z (stride 160) / s_out (stride 288)
  __shared__ float s_sh[EPB][12];
  __shared__ float s_basis[EPB][NB];
  __shared__ float s_h[EPB][20];

  const int tid = threadIdx.x;
  const int e0 = blockIdx.x * EPB;
  const int gq = tid >> 5;        // 0..7  edge quad
  const int w  = tid & 31;        // 0..31 output column within irrep

  // ---- phase 1: sh + radial basis ----
  for (int i = tid; i < EPB * DIM_SHD; i += BLOCK) {
    int zg = i / DIM_SHD, c = i - zg * DIM_SHD;
    s_sh[zg][c] = shg[(size_t)(e0 + zg) * DIM_SHD + c];
  }
  for (int i = tid; i < EPB * NB; i += BLOCK) {
    int zg = i / NB, n = i - zg * NB;
    float d  = dist[e0 + zg];
    float xv = d * 0.25f;
    float x2 = xv * xv, x4 = x2 * x2, x5 = x4 * xv;
    float env = 1.0f / xv + x5 * fmaf(xv, fmaf(xv, -21.0f, 48.0f), -28.0f);
    env = (xv < 1.0f) ? env : 0.0f;
    s_basis[zg][n] = env * sinf(freq[n] * xv);
  }
  __syncthreads();
  // ---- radial MLP hidden layer ----
  for (int i = tid; i < EPB * NH; i += BLOCK) {
    int zg = i >> 4, t = i & 15;
    float v = b1[t];
    #pragma unroll
    for (int n = 0; n < NB; ++n) v = fmaf(s_basis[zg][n], W1[n * NH + t], v);
    s_h[zg][t] = v / (1.0f + expf(-v));   // silu
  }
  __syncthreads();

  // ---- h for my 4 edges into registers ----
  float h[4][NH];
  #pragma unroll
  for (int e = 0; e < 4; ++e) {
    #pragma unroll
    for (int t = 0; t < NH; ++t) h[e][t] = s_h[4 * gq + e][t];
  }

  float acc[4][9];
  #pragma unroll
  for (int e = 0; e < 4; ++e)
    #pragma unroll
    for (int a = 0; a < 9; ++a) acc[e][a] = 0.f;

  //        INS D1 D2 D3 OFF1 OFF2 SB
  run_instr< 0, 1, 1, 1,   0,  0,  0>(tid, e0, gq, w, xg, W2t, b2, s_sh, s_pool, h, acc);
  run_instr< 1, 1, 3, 3,   0,  1,  1>(tid, e0, gq, w, xg, W2t, b2, s_sh, s_pool, h, acc);
  run_instr< 2, 1, 5, 5,   0,  4,  4>(tid, e0, gq, w, xg, W2t, b2, s_sh, s_pool, h, acc);
  run_instr< 3, 3, 1, 3,  32,  0,  1>(tid, e0, gq, w, xg, W2t, b2, s_sh, s_pool, h, acc);
  run_instr< 4, 3, 3, 1,  32,  1,  0>(tid, e0, gq, w, xg, W2t, b2, s_sh, s_pool, h, acc);
  run_instr< 5, 3, 3, 5,  32,  1,  4>(tid, e0, gq, w, xg, W2t, b2, s_sh, s_pool, h, acc);
  run_instr< 6, 3, 5, 3,  32,  4,  1>(tid, e0, gq, w, xg, W2t, b2, s_sh, s_pool, h, acc);
  run_instr< 7, 5, 1, 5, 128,  0,  4>(tid, e0, gq, w, xg, W2t, b2, s_sh, s_pool, h, acc);
  run_instr< 8, 5, 3, 3, 128,  1,  1>(tid, e0, gq, w, xg, W2t, b2, s_sh, s_pool, h, acc);
  run_instr< 9, 5, 5, 1, 128,  4,  0>(tid, e0, gq, w, xg, W2t, b2, s_sh, s_pool, h, acc);
  run_instr<10, 5, 5, 5, 128,  4,  4>(tid, e0, gq, w, xg, W2t, b2, s_sh, s_pool, h, acc);

  // ---- gather into s_out (aliases s_z region) then coalesced store ----
  __syncthreads();   // everyone done reading s_z
  #pragma unroll
  for (int e = 0; e < 4; ++e) {
    float* row = s_pool + (4 * gq + e) * 288;
    row[w] = acc[e][0];
    #pragma unroll
    for (int k = 0; k < 3; ++k) row[32 + w * 3 + k] = acc[e][1 + k];
    #pragma unroll
    for (int k = 0; k < 5; ++k) row[128 + w * 5 + k] = acc[e][4 + k];
  }
  __syncthreads();
  {
    int r = tid >> 3, c0 = (tid & 7) * 36;
    const float* src = s_pool + r * 288 + c0;
    float* dst = out + (size_t)(e0 + r) * DIM_IN + c0;
    #pragma unroll
    for (int j = 0; j < 9; ++j)
      *reinterpret_cast<float4*>(dst + 4 * j) =
          *reinterpret_cast<const float4*>(src + 4 * j);
  }
}

// ===================== host-side Wigner-3j (mirrors reference) =====================
typedef std::complex<double> cd;

static double factd(int n) { double r = 1; for (int i = 2; i <= n; ++i) r *= i; return r; }

static double su2_cg(int j1, int j2, int j3, int m1, int m2, int m3) {
  if (m3 != m1 + m2) return 0.0;
  int vmin = std::max(std::max(-j1 + j2 + m3, -j1 + m1), 0);
  int vmax = std::min(std::min(j2 + j3 + m1, j3 - j1 + j2), j3 + m3);
  if (vmax < vmin) return 0.0;
  double c = std::sqrt(
      factd(2*j3+1) * factd(j3+j1-j2) * factd(j3-j1+j2) * factd(j1+j2-j3) / factd(j1+j2+j3+1)
      * factd(j3+m3) * factd(j3-m3)
      / (factd(j1+m1) * factd(j1-m1) * factd(j2+m2) * factd(j2-m2)));
  double s = 0.0;
  for (int v = vmin; v <= vmax; ++v) {
    double sg = ((v + j2 + m2) & 1) ? -1.0 : 1.0;
    s += sg * factd(j2+j3+m1-v) * factd(j1-m1+v)
         / (factd(v) * factd(j3-j1+j2-v) * factd(j3+m3-v) * factd(v+j1-j2-m3));
  }
  return c * s;
}

static void qmat(int l, cd q[5][5]) {
  for (int a = 0; a < 5; ++a) for (int b = 0; b < 5; ++b) q[a][b] = cd(0, 0);
  const double s = 1.0 / std::sqrt(2.0);
  for (int m = -l; m < 0; ++m) {
    q[l + m][l - m] = cd(s, 0);
    q[l + m][l + m] = cd(0, -s);
  }
  q[l][l] = cd(1, 0);
  for (int m = 1; m <= l; ++m) {
    double sg = (m & 1) ? -1.0 : 1.0;
    q[l + m][l + m] = cd(sg * s, 0);
    q[l + m][l - m] = cd(0, sg * s);
  }
  cd ph = (l == 0) ? cd(1, 0) : (l == 1) ? cd(0, -1) : cd(-1, 0);  // (-i)^l
  for (int a = 0; a < 5; ++a) for (int b = 0; b < 5; ++b) q[a][b] *= ph;
}

static void wigner3j(int l1, int l2, int l3, double C[5][5][5]) {
  int d1 = 2*l1+1, d2 = 2*l2+1, d3 = 2*l3+1;
  cd q1[5][5], q2[5][5], q3[5][5];
  qmat(l1, q1); qmat(l2, q2); qmat(l3, q3);
  double norm2 = 0;
  for (int j = 0; j < d1; ++j)
    for (int l = 0; l < d2; ++l)
      for (int n = 0; n < d3; ++n) {
        cd sum(0, 0);
        for (int i = 0; i < d1; ++i)
          for (int k = 0; k < d2; ++k)
            for (int m = 0; m < d3; ++m) {
              double cg = su2_cg(l1, l2, l3, i - l1, k - l2, m - l3);
              if (cg != 0.0) sum += q1[i][j] * q2[k][l] * std::conj(q3[m][n]) * cg;
            }
        C[j][l][n] = sum.real();
        norm2 += C[j][l][n] * C[j][l][n];
      }
  double nrm = std::sqrt(norm2);
  if (nrm > 0)
    for (int j = 0; j < d1; ++j)
      for (int l = 0; l < d2; ++l)
        for (int n = 0; n < d3; ++n) C[j][l][n] /= nrm;
}

static void build_C_host(float C_out[NINSTR][125]) {
  const int L1[NINSTR] = {0,0,0,1,1,1,1,2,2,2,2};
  const int L2[NINSTR] = {0,1,2,0,1,1,2,0,1,2,2};
  const int L3[NINSTR] = {0,1,2,1,0,2,1,2,1,0,2};
  std::memset(C_out, 0, sizeof(float) * NINSTR * 125);
  for (int ins = 0; ins < NINSTR; ++ins) {
    int l1 = L1[ins], l2 = L2[ins], l3 = L3[ins];
    int d1 = 2*l1+1, d2 = 2*l2+1, d3 = 2*l3+1;
    double C[5][5][5];
    wigner3j(l1, l2, l3, C);
    double fan = (l3 == 0) ? 96.0 : 128.0;
    double pw = std::sqrt((2*l3+1) / fan);
    for (int i = 0; i < d1; ++i)
      for (int j = 0; j < d2; ++j)
        for (int k = 0; k < d3; ++k)
          C_out[ins][(i * d2 + j) * d3 + k] = (float)(pw * C[i][j][k]);
  }
}

extern "C" void kernel_launch(void* const* d_in, const int* in_sizes, int n_in,
                              void* d_out, int out_size, void* d_ws, size_t ws_size,
                              hipStream_t stream) {
  static float hC[NINSTR][125];
  build_C_host(hC);
  void* dC = nullptr;
  hipGetSymbolAddress(&dC, HIP_SYMBOL(g_C));
  hipMemcpyAsync(dC, hC, sizeof(hC), hipMemcpyHostToDevice, stream);

  const float* xg   = (const float*)d_in[0];
  const float* shg  = (const float*)d_in[1];
  const float* dist = (const float*)d_in[2];
  const float* freq = (const float*)d_in[3];
  const float* W1   = (const float*)d_in[4];
  const float* b1   = (const float*)d_in[5];
  const float* W2   = (const float*)d_in[6];
  const float* b2   = (const float*)d_in[7];
  float* out = (float*)d_out;
  float* W2t = (float*)d_ws;                 // 720896 bytes

  transpose_w2<<<(W2T_ELEMS + 255) / 256, 256, 0, stream>>>(W2, W2t);

  int E = in_sizes[2];            // 16384
  int blocks = E / EPB;           // 512
  conv_kernel<<<blocks, BLOCK, 0, stream>>>(xg, shg, dist, freq, W1, b1, W2t, b2, out);
}